// Round 10
// baseline (167.917 us; speedup 1.0000x reference)
//
#include <hip/hip_runtime.h>
#include <hip/hip_bf16.h>

// DynamicGCN: 2 layers of { h = relu(x@W+b); h += segment_sum(ew*h[src], dst); LN(h) }
// N=50000, E=800000, D=128.
// r10: aggln is L2-miss-traffic bound (r9: deeper MLP flat) -> attack overhead:
//  (1) k_bfinal fused with gemm-L1 (independent deps; bfinal hides under gemm).
//  (2) k_bhist writes per-block partials (no global atomics, no pre-zero);
//      k_prep merged in; k_bscan reduces partials. 9 -> 7 launches.
//  (3) csr packed to 4B/edge {src16 | bf16(w)<<16}: halves csr traffic.

#define D 128
#define SA 8192   // edges per block in hist/fill passes

typedef __attribute__((ext_vector_type(8))) short short8;
typedef __attribute__((ext_vector_type(4))) float f32x4;
typedef __attribute__((ext_vector_type(2))) unsigned int uint2v;
typedef __attribute__((ext_vector_type(4))) unsigned int uint4v;

// ---- A: per-block bucket histogram partials (no atomics) + W prep ----
__global__ __launch_bounds__(1024) void k_hist_prep(
        const int* __restrict__ dst, int e, int n, int nb, int nblk,
        int* __restrict__ part,
        const float* __restrict__ W1, const float* __restrict__ W2,
        short* __restrict__ WT1, short* __restrict__ WT2) {
    __shared__ int lh[784];
    int b = blockIdx.x, tid = threadIdx.x;
    if (b < nblk) {
        for (int i = tid; i < nb; i += 1024) lh[i] = 0;
        __syncthreads();
        int i0 = b * SA;
#pragma unroll
        for (int k = 0; k < SA / 1024; ++k) {
            int i = i0 + k * 1024 + tid;
            if (i < e) {
                int d = dst[i];
                d = min(max(d, 0), n - 1);
                atomicAdd(&lh[d >> 6], 1);
            }
        }
        __syncthreads();
        for (int i = tid; i < nb; i += 1024) part[b * nb + i] = lh[i];
    } else {
        int q = b - nblk;           // 0..31
        int i = q * 1024 + tid;     // 0..32767 over W1(16384) then W2(16384)
        if (i < 16384) {
            int k = i >> 7, nn = i & 127;
            WT1[nn * 128 + k] = (short)__bfloat16_as_ushort(__float2bfloat16(W1[i]));
        } else {
            int j = i - 16384;
            int k = j >> 7, nn = j & 127;
            WT2[nn * 128 + k] = (short)__bfloat16_as_ushort(__float2bfloat16(W2[j]));
        }
    }
}

// ---- B: reduce partials + exclusive scan (nb <= 1024) ----
__global__ __launch_bounds__(1024) void k_bscan(const int* __restrict__ part,
                                                int nb, int nblk,
                                                int* __restrict__ boff,
                                                int* __restrict__ bcursor) {
    __shared__ int s[1024];
    int t = threadIdx.x;
    int v = 0;
    if (t < nb)
        for (int blk = 0; blk < nblk; ++blk) v += part[blk * nb + t];
    s[t] = v;
    __syncthreads();
    for (int off = 1; off < 1024; off <<= 1) {
        int u = (t >= off) ? s[t - off] : 0;
        __syncthreads();
        s[t] += u;
        __syncthreads();
    }
    if (t < nb) {
        int ex = s[t] - v;
        boff[t] = ex;
        bcursor[t] = ex;
    }
}

// ---- C: binning fill; (block,bucket) runs reserved once -> XCD-local stores ----
__global__ __launch_bounds__(1024) void k_bfill(const int* __restrict__ src,
                                                const int* __restrict__ dst,
                                                const float* __restrict__ ew, int e,
                                                int n, int nb,
                                                int* __restrict__ bcursor,
                                                uint2v* __restrict__ csr_tmp) {
    __shared__ int lh[784];
    __shared__ int gbase[784];
    int tid = threadIdx.x;
    for (int i = tid; i < nb; i += 1024) lh[i] = 0;
    __syncthreads();
    int i0 = blockIdx.x * SA;
    int bkt[SA / 1024], pos[SA / 1024];
    unsigned pk[SA / 1024];
    float wv[SA / 1024];
#pragma unroll
    for (int k = 0; k < SA / 1024; ++k) {
        int i = i0 + k * 1024 + tid;
        bkt[k] = -1;
        if (i < e) {
            int d = dst[i];
            d = min(max(d, 0), n - 1);
            int s = src[i];
            s = min(max(s, 0), n - 1);
            int b = d >> 6;
            bkt[k] = b;
            pos[k] = atomicAdd(&lh[b], 1);
            pk[k] = (unsigned)s | ((unsigned)(d & 63) << 16);
            wv[k] = ew[i];
        }
    }
    __syncthreads();
    for (int i = tid; i < nb; i += 1024)
        gbase[i] = lh[i] ? atomicAdd(&bcursor[i], lh[i]) : 0;
    __syncthreads();
#pragma unroll
    for (int k = 0; k < SA / 1024; ++k) {
        if (bkt[k] >= 0) {
            int idx = gbase[bkt[k]] + pos[k];
            uint2v en;
            en.x = pk[k];
            en.y = __float_as_uint(wv[k]);
            csr_tmp[idx] = en;
        }
    }
}

// ---- MFMA GEMM body: h_bf16 = relu(x@W + b); block = 16-row tile/step, waves
// split cols (wave w: n-tiles {w,w+4}); A prefetched one stride ahead.
// A: row=lane&15, k=(lane>>4)*8+i ; B: col=lane&15 ; D: col=lane&15,
// row=(lane>>4)*4+reg  [r5-verified]
__device__ __forceinline__ short8 cvt8v(f32x4 lo, f32x4 hi) {
    short8 r;
    r[0] = (short)__bfloat16_as_ushort(__float2bfloat16(lo.x));
    r[1] = (short)__bfloat16_as_ushort(__float2bfloat16(lo.y));
    r[2] = (short)__bfloat16_as_ushort(__float2bfloat16(lo.z));
    r[3] = (short)__bfloat16_as_ushort(__float2bfloat16(lo.w));
    r[4] = (short)__bfloat16_as_ushort(__float2bfloat16(hi.x));
    r[5] = (short)__bfloat16_as_ushort(__float2bfloat16(hi.y));
    r[6] = (short)__bfloat16_as_ushort(__float2bfloat16(hi.z));
    r[7] = (short)__bfloat16_as_ushort(__float2bfloat16(hi.w));
    return r;
}

template <int F32IN>
__device__ __forceinline__ void gemm_body(int bid, int nblocks,
                                          const float* __restrict__ xf,
                                          const short* __restrict__ xb,
                                          const short* __restrict__ WT,
                                          const float* __restrict__ bias,
                                          ushort* __restrict__ hb, int n) {
    int lane = threadIdx.x & 63;
    int w = threadIdx.x >> 6;  // 0..3
    int ln = lane & 15, g = lane >> 4;
    int nt0 = w, nt1 = w + 4;
    short8 bfr0[4], bfr1[4];
#pragma unroll
    for (int kk = 0; kk < 4; ++kk) {
        bfr0[kk] = *(const short8*)(WT + (nt0 * 16 + ln) * 128 + kk * 32 + g * 8);
        bfr1[kk] = *(const short8*)(WT + (nt1 * 16 + ln) * 128 + kk * 32 + g * 8);
    }
    float bv0 = bias[nt0 * 16 + ln];
    float bv1 = bias[nt1 * 16 + ln];

    int ntile = n >> 4;  // n % 16 == 0 (50000)
    int t = bid;
    if (t >= ntile) return;

    f32x4 cf[8];
    short8 cb[4];
    auto LOADA = [&](int tt, f32x4* bf, short8* bb) {
        int row = tt * 16 + ln;
        if (F32IN) {
            const f32x4* p = (const f32x4*)(xf + (size_t)row * 128 + g * 8);
#pragma unroll
            for (int kk = 0; kk < 4; ++kk) {
                bf[kk * 2] = p[kk * 8];
                bf[kk * 2 + 1] = p[kk * 8 + 1];
            }
        } else {
            const short8* p = (const short8*)(xb + (size_t)row * 128 + g * 8);
#pragma unroll
            for (int kk = 0; kk < 4; ++kk) bb[kk] = p[kk * 4];
        }
    };
    LOADA(t, cf, cb);
    while (true) {
        int tn = t + nblocks;
        f32x4 nf[8];
        short8 nb_[4];
        if (tn < ntile) LOADA(tn, nf, nb_);  // prefetch next tile's A
        short8 a[4];
        if (F32IN) {
#pragma unroll
            for (int kk = 0; kk < 4; ++kk) a[kk] = cvt8v(cf[kk * 2], cf[kk * 2 + 1]);
        } else {
#pragma unroll
            for (int kk = 0; kk < 4; ++kk) a[kk] = cb[kk];
        }
        f32x4 acc0 = {}, acc1 = {};
#pragma unroll
        for (int kk = 0; kk < 4; ++kk) {
            acc0 = __builtin_amdgcn_mfma_f32_16x16x32_bf16(a[kk], bfr0[kk], acc0, 0, 0, 0);
            acc1 = __builtin_amdgcn_mfma_f32_16x16x32_bf16(a[kk], bfr1[kk], acc1, 0, 0, 0);
        }
        int r0 = t * 16 + g * 4;
#pragma unroll
        for (int r = 0; r < 4; ++r) {
            float v0 = fmaxf(acc0[r] + bv0, 0.0f);
            float v1 = fmaxf(acc1[r] + bv1, 0.0f);
            hb[(size_t)(r0 + r) * 128 + nt0 * 16 + ln] =
                __bfloat16_as_ushort(__float2bfloat16(v0));
            hb[(size_t)(r0 + r) * 128 + nt1 * 16 + ln] =
                __bfloat16_as_ushort(__float2bfloat16(v1));
        }
        if (tn >= ntile) break;
#pragma unroll
        for (int i = 0; i < 8; ++i) cf[i] = nf[i];
#pragma unroll
        for (int i = 0; i < 4; ++i) cb[i] = nb_[i];
        t = tn;
    }
}

// ---- D fused with gemm-L1: blocks [0,nb) = per-bucket regroup (LDS-staged,
// emits row_ptr + 4B csr {src16|bf16(w)<<16}); blocks [nb, nb+gemm_blocks) =
// gemm layer 1 (independent deps: csr_tmp vs x/WT1) ----
#define STG 3072
__global__ __launch_bounds__(256) void k_final_gemm1(
        const uint2v* __restrict__ csr_tmp, const int* __restrict__ boff,
        int n, int e, int nb,
        int* __restrict__ row_ptr, uint* __restrict__ csr4,
        const float* __restrict__ xf, const short* __restrict__ WT1,
        const float* __restrict__ bias1, ushort* __restrict__ hb,
        int gemm_blocks) {
    __shared__ uint2v stage[STG];
    __shared__ int dh[64], dcur[64], dscan[64];
    int b = blockIdx.x;
    int tid = threadIdx.x;
    if (b >= nb) {
        gemm_body<1>(b - nb, gemm_blocks, xf, nullptr, WT1, bias1, hb, n);
        return;
    }
    int base = boff[b];
    int endo = (b + 1 < nb) ? boff[b + 1] : e;
    int cnt = endo - base;
    int ndst = min(64, n - b * 64);
    bool st = (cnt <= STG);
    if (tid < 64) { dh[tid] = 0; dcur[tid] = 0; }
    __syncthreads();
    for (int i = tid; i < cnt; i += 256) {
        uint2v en = csr_tmp[base + i];
        if (st) stage[i] = en;
        atomicAdd(&dh[(en.x >> 16) & 63], 1);
    }
    __syncthreads();
    if (tid < 64) {
        int v = dh[tid];
        int incl = v;
#pragma unroll
        for (int off = 1; off < 64; off <<= 1) {
            int u = __shfl_up(incl, off, 64);
            if (tid >= off) incl += u;
        }
        dscan[tid] = incl - v;  // exclusive
        if (tid < ndst) row_ptr[b * 64 + tid] = base + incl - v;
        if (b == nb - 1 && tid == 0) row_ptr[n] = e;
    }
    __syncthreads();
    for (int i = tid; i < cnt; i += 256) {
        uint2v en = st ? stage[i] : csr_tmp[base + i];
        int dlo = (en.x >> 16) & 63;
        int p = atomicAdd(&dcur[dlo], 1);
        uint packed = (en.x & 0xffffu) |
                      ((uint)__bfloat16_as_ushort(
                           __float2bfloat16(__uint_as_float(en.y))) << 16);
        csr4[base + dscan[dlo] + p] = packed;
    }
}

// ---- standalone gemm (layer 2) ----
template <int F32IN>
__global__ __launch_bounds__(256) void k_gemm(const float* __restrict__ xf,
                                              const short* __restrict__ xb,
                                              const short* __restrict__ WT,
                                              const float* __restrict__ bias,
                                              ushort* __restrict__ hb, int n,
                                              int nblocks) {
    gemm_body<F32IN>(blockIdx.x, nblocks, xf, xb, WT, bias, hb, n);
}

// ---- fused aggregation + LayerNorm; csr entry = {src16 | bf16(w)<<16} ----
// Wave per node; 16 lanes per h-row (sub=lane>>4 handles edge j+4k+sub,
// c=lane&15 owns a 16B chunk). 16-edge loop: 4 independent row-gathers.
__global__ __launch_bounds__(256) void k_aggln(const ushort* __restrict__ hb,
                                               const float* __restrict__ gamma,
                                               const float* __restrict__ beta,
                                               const int* __restrict__ row_ptr,
                                               const uint* __restrict__ csru,
                                               float* __restrict__ out,
                                               uint* __restrict__ xb_out,
                                               int n) {
    int wid = threadIdx.x >> 6;
    int lane = threadIdx.x & 63;
    int node = blockIdx.x * 4 + wid;
    if (node >= n) return;
    int sub = lane >> 4, c = lane & 15;
    const uint4v* hb4 = (const uint4v*)hb;  // row = 16 chunks of 16B

    float acc[8] = {0.f, 0.f, 0.f, 0.f, 0.f, 0.f, 0.f, 0.f};
    auto ACC8 = [&](uint4v r, float wgt) {
        acc[0] += wgt * __uint_as_float(r.x << 16);
        acc[1] += wgt * __uint_as_float(r.x & 0xffff0000u);
        acc[2] += wgt * __uint_as_float(r.y << 16);
        acc[3] += wgt * __uint_as_float(r.y & 0xffff0000u);
        acc[4] += wgt * __uint_as_float(r.z << 16);
        acc[5] += wgt * __uint_as_float(r.z & 0xffff0000u);
        acc[6] += wgt * __uint_as_float(r.w << 16);
        acc[7] += wgt * __uint_as_float(r.w & 0xffff0000u);
    };

    int beg = row_ptr[node], end = row_ptr[node + 1];
    int j = beg;
    for (; j + 16 <= end; j += 16) {  // 16 edges/iter: 4 gathers in flight
        uint e0 = csru[j + sub];
        uint e1 = csru[j + 4 + sub];
        uint e2 = csru[j + 8 + sub];
        uint e3 = csru[j + 12 + sub];
        uint4v r0 = hb4[(e0 & 0xffffu) * 16 + c];
        uint4v r1 = hb4[(e1 & 0xffffu) * 16 + c];
        uint4v r2 = hb4[(e2 & 0xffffu) * 16 + c];
        uint4v r3 = hb4[(e3 & 0xffffu) * 16 + c];
        ACC8(r0, __uint_as_float(e0 & 0xffff0000u));
        ACC8(r1, __uint_as_float(e1 & 0xffff0000u));
        ACC8(r2, __uint_as_float(e2 & 0xffff0000u));
        ACC8(r3, __uint_as_float(e3 & 0xffff0000u));
    }
    for (; j < end; j += 4) {  // tail, masked
        int jj = j + sub;
        uint ee = csru[jj < end ? jj : (end - 1)];
        float wgt = (jj < end) ? __uint_as_float(ee & 0xffff0000u) : 0.0f;
        uint idx = (jj < end) ? (ee & 0xffffu) : (uint)node;
        uint4v r = hb4[idx * 16 + c];
        ACC8(r, wgt);
    }
    // reduce the 4 sub-group partials
#pragma unroll
    for (int i = 0; i < 8; ++i) {
        acc[i] += __shfl_xor(acc[i], 16, 64);
        acc[i] += __shfl_xor(acc[i], 32, 64);
    }
    // self term
    {
        uint4v s = hb4[(uint)node * 16 + c];
        ACC8(s, 1.0f);
    }
    // LayerNorm over 128 (16 c-lanes x 8)
    float sum = acc[0] + acc[1] + acc[2] + acc[3] + acc[4] + acc[5] + acc[6] + acc[7];
#pragma unroll
    for (int m = 1; m < 16; m <<= 1) sum += __shfl_xor(sum, m, 64);
    float mean = sum * (1.0f / 128.0f);
    float d0 = acc[0] - mean, d1 = acc[1] - mean, d2 = acc[2] - mean, d3 = acc[3] - mean;
    float d4 = acc[4] - mean, d5 = acc[5] - mean, d6 = acc[6] - mean, d7 = acc[7] - mean;
    float ss = d0 * d0 + d1 * d1 + d2 * d2 + d3 * d3 + d4 * d4 + d5 * d5 + d6 * d6 + d7 * d7;
#pragma unroll
    for (int m = 1; m < 16; m <<= 1) ss += __shfl_xor(ss, m, 64);
    float rstd = rsqrtf(ss * (1.0f / 128.0f) + 1e-5f);
    f32x4 gA = ((const f32x4*)gamma)[c * 2], gB = ((const f32x4*)gamma)[c * 2 + 1];
    f32x4 bA = ((const f32x4*)beta)[c * 2], bB = ((const f32x4*)beta)[c * 2 + 1];
    f32x4 oA, oB;
    oA.x = d0 * rstd * gA.x + bA.x;
    oA.y = d1 * rstd * gA.y + bA.y;
    oA.z = d2 * rstd * gA.z + bA.z;
    oA.w = d3 * rstd * gA.w + bA.w;
    oB.x = d4 * rstd * gB.x + bB.x;
    oB.y = d5 * rstd * gB.y + bB.y;
    oB.z = d6 * rstd * gB.z + bB.z;
    oB.w = d7 * rstd * gB.w + bB.w;
    if (sub == 0) {
        if (out) {
            f32x4* po = (f32x4*)(out + (size_t)node * 128 + c * 8);
            po[0] = oA;
            po[1] = oB;
        }
        if (xb_out) {
            uint4v u;
            u.x = (uint)__bfloat16_as_ushort(__float2bfloat16(oA.x)) |
                  ((uint)__bfloat16_as_ushort(__float2bfloat16(oA.y)) << 16);
            u.y = (uint)__bfloat16_as_ushort(__float2bfloat16(oA.z)) |
                  ((uint)__bfloat16_as_ushort(__float2bfloat16(oA.w)) << 16);
            u.z = (uint)__bfloat16_as_ushort(__float2bfloat16(oB.x)) |
                  ((uint)__bfloat16_as_ushort(__float2bfloat16(oB.y)) << 16);
            u.w = (uint)__bfloat16_as_ushort(__float2bfloat16(oB.z)) |
                  ((uint)__bfloat16_as_ushort(__float2bfloat16(oB.w)) << 16);
            ((uint4v*)xb_out)[node * 16 + c] = u;
        }
    }
}

extern "C" void kernel_launch(void* const* d_in, const int* in_sizes, int n_in,
                              void* d_out, int out_size, void* d_ws, size_t ws_size,
                              hipStream_t stream) {
    const float* x   = (const float*)d_in[0];
    const int*  eidx = (const int*)d_in[1];   // [2,E]: src=eidx, dst=eidx+e
    const float* ew  = (const float*)d_in[2];
    const float* W1  = (const float*)d_in[3];
    const float* b1  = (const float*)d_in[4];
    const float* g1  = (const float*)d_in[5];
    const float* be1 = (const float*)d_in[6];
    const float* W2  = (const float*)d_in[7];
    const float* b2  = (const float*)d_in[8];
    const float* g2  = (const float*)d_in[9];
    const float* be2 = (const float*)d_in[10];
    int n = in_sizes[0] / D;
    int e = in_sizes[2];
    const int* srcp = eidx;
    const int* dstp = eidx + e;

    char* ws = (char*)d_ws;
    size_t off = 0;
    auto alloc = [&](size_t bytes) {
        void* p = ws + off;
        off += (bytes + 255) & ~(size_t)255;
        return p;
    };
    ushort* hb      = (ushort*)alloc((size_t)n * D * sizeof(ushort));
    uint*   xb      = (uint*)alloc((size_t)n * (D / 2) * sizeof(uint));
    int*    row_ptr = (int*)alloc((size_t)(n + 1) * sizeof(int));
    int*    boff    = (int*)alloc(1024 * sizeof(int));
    int*    bcursor = (int*)alloc(1024 * sizeof(int));
    short*  WT1     = (short*)alloc(128 * 128 * sizeof(short));
    short*  WT2     = (short*)alloc(128 * 128 * sizeof(short));
    uint2v* csr_tmp = (uint2v*)alloc((size_t)e * sizeof(uint2v));
    uint*   csr4    = (uint*)alloc((size_t)e * sizeof(uint));

    int nb = (n + 63) >> 6;              // 782 buckets (<=1024)
    int nblk = (e + SA - 1) / SA;        // 98 edge blocks
    int* part = (int*)alloc((size_t)nblk * nb * sizeof(int));  // hist partials

    // ---- build dst-grouped CSR via 2-level counting sort ----
    k_hist_prep<<<nblk + 32, 1024, 0, stream>>>(dstp, e, n, nb, nblk, part,
                                                W1, W2, WT1, WT2);
    k_bscan<<<1, 1024, 0, stream>>>(part, nb, nblk, boff, bcursor);
    k_bfill<<<nblk, 1024, 0, stream>>>(srcp, dstp, ew, e, n, nb, bcursor, csr_tmp);

    // ---- bfinal || gemm layer-1 (independent deps) ----
    k_final_gemm1<<<nb + 512, 256, 0, stream>>>(csr_tmp, boff, n, e, nb, row_ptr,
                                                csr4, x, WT1, b1, hb, 512);
    // ---- layer 1 aggregation (writes bf16 xb only) ----
    k_aggln<<<(n + 3) / 4, 256, 0, stream>>>(hb, g1, be1, row_ptr, csr4,
                                             nullptr, xb, n);
    // ---- layer 2 ----
    k_gemm<0><<<512, 256, 0, stream>>>(nullptr, (const short*)xb, WT2, b2, hb, n, 512);
    k_aggln<<<(n + 3) / 4, 256, 0, stream>>>(hb, g2, be2, row_ptr, csr4,
                                             (float*)d_out, nullptr, n);
}

// Round 11
// 140.047 us; speedup vs baseline: 1.1990x; 1.1990x over previous
//
#include <hip/hip_runtime.h>
#include <hip/hip_bf16.h>

// DynamicGCN: 2 layers of { h = relu(x@W+b); h += segment_sum(ew*h[src], dst); LN(h) }
// N=50000, E=800000, D=128.
// r11: r9 structure restored verbatim (r10's launch-fusion + hist-partials
//      regressed +25us; cause not attributable -> single-variable round).
//      Only retained r10 change: csr packed to 4B/edge {src16 | bf16(w)<<16}
//      (absmax 0.0332 verified in r10; halves csr write+read traffic).

#define D 128
#define SA 8192   // edges per block in hist/fill passes

typedef __attribute__((ext_vector_type(8))) short short8;
typedef __attribute__((ext_vector_type(4))) float f32x4;
typedef __attribute__((ext_vector_type(2))) unsigned int uint2v;
typedef __attribute__((ext_vector_type(4))) unsigned int uint4v;

// ---- prep: zero bhist (block 128) + WT[n][k]=bf16(W[k][n]) (blocks 0..127) ----
__global__ __launch_bounds__(256) void k_prep(const float* __restrict__ W1,
                                              const float* __restrict__ W2,
                                              short* __restrict__ WT1,
                                              short* __restrict__ WT2,
                                              int* __restrict__ bhist, int nb) {
    int b = blockIdx.x;
    if (b < 128) {
        const float* W = (b < 64) ? W1 : W2;
        short* WT = (b < 64) ? WT1 : WT2;
        int i = (b & 63) * 256 + threadIdx.x;  // 0..16383
        int k = i >> 7, nn = i & 127;
        WT[nn * 128 + k] = (short)__bfloat16_as_ushort(__float2bfloat16(W[i]));
    } else {
        for (int i = threadIdx.x; i < nb; i += 256) bhist[i] = 0;
    }
}

// ---- A: global bucket histogram (bucket = dst>>6) ----
__global__ __launch_bounds__(1024) void k_bhist(const int* __restrict__ dst, int e,
                                                int n, int nb,
                                                int* __restrict__ bhist) {
    __shared__ int lh[784];
    int tid = threadIdx.x;
    for (int i = tid; i < nb; i += 1024) lh[i] = 0;
    __syncthreads();
    int i0 = blockIdx.x * SA;
#pragma unroll
    for (int k = 0; k < SA / 1024; ++k) {
        int i = i0 + k * 1024 + tid;
        if (i < e) {
            int d = dst[i];
            d = min(max(d, 0), n - 1);
            atomicAdd(&lh[d >> 6], 1);
        }
    }
    __syncthreads();
    for (int i = tid; i < nb; i += 1024)
        if (lh[i]) atomicAdd(&bhist[i], lh[i]);
}

// ---- B: exclusive scan of bhist (nb <= 1024); bcursor starts at boff ----
__global__ __launch_bounds__(1024) void k_bscan(const int* __restrict__ bhist, int nb,
                                                int* __restrict__ boff,
                                                int* __restrict__ bcursor) {
    __shared__ int s[1024];
    int t = threadIdx.x;
    int v = (t < nb) ? bhist[t] : 0;
    s[t] = v;
    __syncthreads();
    for (int off = 1; off < 1024; off <<= 1) {
        int u = (t >= off) ? s[t - off] : 0;
        __syncthreads();
        s[t] += u;
        __syncthreads();
    }
    if (t < nb) {
        int ex = s[t] - v;
        boff[t] = ex;
        bcursor[t] = ex;
    }
}

// ---- C: binning fill; (block,bucket) runs reserved once -> XCD-local stores ----
__global__ __launch_bounds__(1024) void k_bfill(const int* __restrict__ src,
                                                const int* __restrict__ dst,
                                                const float* __restrict__ ew, int e,
                                                int n, int nb,
                                                int* __restrict__ bcursor,
                                                uint2v* __restrict__ csr_tmp) {
    __shared__ int lh[784];
    __shared__ int gbase[784];
    int tid = threadIdx.x;
    for (int i = tid; i < nb; i += 1024) lh[i] = 0;
    __syncthreads();
    int i0 = blockIdx.x * SA;
    int bkt[SA / 1024], pos[SA / 1024];
    unsigned pk[SA / 1024];
    float wv[SA / 1024];
#pragma unroll
    for (int k = 0; k < SA / 1024; ++k) {
        int i = i0 + k * 1024 + tid;
        bkt[k] = -1;
        if (i < e) {
            int d = dst[i];
            d = min(max(d, 0), n - 1);
            int s = src[i];
            s = min(max(s, 0), n - 1);
            int b = d >> 6;
            bkt[k] = b;
            pos[k] = atomicAdd(&lh[b], 1);
            pk[k] = (unsigned)s | ((unsigned)(d & 63) << 16);
            wv[k] = ew[i];
        }
    }
    __syncthreads();
    for (int i = tid; i < nb; i += 1024)
        gbase[i] = lh[i] ? atomicAdd(&bcursor[i], lh[i]) : 0;
    __syncthreads();
#pragma unroll
    for (int k = 0; k < SA / 1024; ++k) {
        if (bkt[k] >= 0) {
            int idx = gbase[bkt[k]] + pos[k];
            uint2v en;
            en.x = pk[k];
            en.y = __float_as_uint(wv[k]);
            csr_tmp[idx] = en;
        }
    }
}

// ---- D: per-bucket exact regroup by dst; LDS-staged; emits row_ptr +
// 4B-packed csr {src16 | bf16(w)<<16} ----
#define STG 3072
__global__ __launch_bounds__(256) void k_bfinal(const uint2v* __restrict__ csr_tmp,
                                                const int* __restrict__ boff, int n,
                                                int e, int nb,
                                                int* __restrict__ row_ptr,
                                                uint* __restrict__ csr4) {
    __shared__ uint2v stage[STG];
    __shared__ int dh[64], dcur[64], dscan[64];
    int b = blockIdx.x;
    int tid = threadIdx.x;
    int base = boff[b];
    int endo = (b + 1 < nb) ? boff[b + 1] : e;
    int cnt = endo - base;
    int ndst = min(64, n - b * 64);
    bool st = (cnt <= STG);
    if (tid < 64) { dh[tid] = 0; dcur[tid] = 0; }
    __syncthreads();
    for (int i = tid; i < cnt; i += 256) {
        uint2v en = csr_tmp[base + i];
        if (st) stage[i] = en;
        atomicAdd(&dh[(en.x >> 16) & 63], 1);
    }
    __syncthreads();
    if (tid < 64) {
        int v = dh[tid];
        int incl = v;
#pragma unroll
        for (int off = 1; off < 64; off <<= 1) {
            int u = __shfl_up(incl, off, 64);
            if (tid >= off) incl += u;
        }
        dscan[tid] = incl - v;  // exclusive
        if (tid < ndst) row_ptr[b * 64 + tid] = base + incl - v;
        if (b == nb - 1 && tid == 0) row_ptr[n] = e;
    }
    __syncthreads();
    for (int i = tid; i < cnt; i += 256) {
        uint2v en = st ? stage[i] : csr_tmp[base + i];
        int dlo = (en.x >> 16) & 63;
        int p = atomicAdd(&dcur[dlo], 1);
        uint packed = (en.x & 0xffffu) |
                      ((uint)__bfloat16_as_ushort(
                           __float2bfloat16(__uint_as_float(en.y))) << 16);
        csr4[base + dscan[dlo] + p] = packed;
    }
}

// ---- MFMA GEMM: h_bf16 = relu(x@W + b); block = one 16-row tile/step, waves
// split cols (wave w: n-tiles {w,w+4}); A prefetched one grid-stride ahead.
// A: row=lane&15, k=(lane>>4)*8+i ; B: col=lane&15 ; D: col=lane&15,
// row=(lane>>4)*4+reg  [r5-verified]
__device__ __forceinline__ short8 cvt8v(f32x4 lo, f32x4 hi) {
    short8 r;
    r[0] = (short)__bfloat16_as_ushort(__float2bfloat16(lo.x));
    r[1] = (short)__bfloat16_as_ushort(__float2bfloat16(lo.y));
    r[2] = (short)__bfloat16_as_ushort(__float2bfloat16(lo.z));
    r[3] = (short)__bfloat16_as_ushort(__float2bfloat16(lo.w));
    r[4] = (short)__bfloat16_as_ushort(__float2bfloat16(hi.x));
    r[5] = (short)__bfloat16_as_ushort(__float2bfloat16(hi.y));
    r[6] = (short)__bfloat16_as_ushort(__float2bfloat16(hi.z));
    r[7] = (short)__bfloat16_as_ushort(__float2bfloat16(hi.w));
    return r;
}

template <int F32IN>
__global__ __launch_bounds__(256) void k_gemm_mfma(const float* __restrict__ xf,
                                                   const short* __restrict__ xb,
                                                   const short* __restrict__ WT,
                                                   const float* __restrict__ bias,
                                                   ushort* __restrict__ hb, int n) {
    int lane = threadIdx.x & 63;
    int w = threadIdx.x >> 6;  // 0..3
    int ln = lane & 15, g = lane >> 4;
    int nt0 = w, nt1 = w + 4;
    short8 bfr0[4], bfr1[4];
#pragma unroll
    for (int kk = 0; kk < 4; ++kk) {
        bfr0[kk] = *(const short8*)(WT + (nt0 * 16 + ln) * 128 + kk * 32 + g * 8);
        bfr1[kk] = *(const short8*)(WT + (nt1 * 16 + ln) * 128 + kk * 32 + g * 8);
    }
    float bv0 = bias[nt0 * 16 + ln];
    float bv1 = bias[nt1 * 16 + ln];

    int ntile = n >> 4;  // n % 16 == 0 (50000)
    int t = blockIdx.x;
    if (t >= ntile) return;

    f32x4 cf[8];
    short8 cb[4];
    auto LOADA = [&](int tt, f32x4* bf, short8* bb) {
        int row = tt * 16 + ln;
        if (F32IN) {
            const f32x4* p = (const f32x4*)(xf + (size_t)row * 128 + g * 8);
#pragma unroll
            for (int kk = 0; kk < 4; ++kk) {
                bf[kk * 2] = p[kk * 8];
                bf[kk * 2 + 1] = p[kk * 8 + 1];
            }
        } else {
            const short8* p = (const short8*)(xb + (size_t)row * 128 + g * 8);
#pragma unroll
            for (int kk = 0; kk < 4; ++kk) bb[kk] = p[kk * 4];
        }
    };
    LOADA(t, cf, cb);
    while (true) {
        int tn = t + (int)gridDim.x;
        f32x4 nf[8];
        short8 nb_[4];
        if (tn < ntile) LOADA(tn, nf, nb_);  // prefetch next tile's A
        short8 a[4];
        if (F32IN) {
#pragma unroll
            for (int kk = 0; kk < 4; ++kk) a[kk] = cvt8v(cf[kk * 2], cf[kk * 2 + 1]);
        } else {
#pragma unroll
            for (int kk = 0; kk < 4; ++kk) a[kk] = cb[kk];
        }
        f32x4 acc0 = {}, acc1 = {};
#pragma unroll
        for (int kk = 0; kk < 4; ++kk) {
            acc0 = __builtin_amdgcn_mfma_f32_16x16x32_bf16(a[kk], bfr0[kk], acc0, 0, 0, 0);
            acc1 = __builtin_amdgcn_mfma_f32_16x16x32_bf16(a[kk], bfr1[kk], acc1, 0, 0, 0);
        }
        int r0 = t * 16 + g * 4;
#pragma unroll
        for (int r = 0; r < 4; ++r) {
            float v0 = fmaxf(acc0[r] + bv0, 0.0f);
            float v1 = fmaxf(acc1[r] + bv1, 0.0f);
            hb[(size_t)(r0 + r) * 128 + nt0 * 16 + ln] =
                __bfloat16_as_ushort(__float2bfloat16(v0));
            hb[(size_t)(r0 + r) * 128 + nt1 * 16 + ln] =
                __bfloat16_as_ushort(__float2bfloat16(v1));
        }
        if (tn >= ntile) break;
#pragma unroll
        for (int i = 0; i < 8; ++i) cf[i] = nf[i];
#pragma unroll
        for (int i = 0; i < 4; ++i) cb[i] = nb_[i];
        t = tn;
    }
}

// ---- fused aggregation + LayerNorm; csr entry = {src16 | bf16(w)<<16} ----
// Wave per node; 16 lanes per h-row (sub=lane>>4 handles edge j+4k+sub,
// c=lane&15 owns a 16B chunk). 16-edge loop: 4 independent row-gathers.
__global__ __launch_bounds__(256) void k_aggln(const ushort* __restrict__ hb,
                                               const float* __restrict__ gamma,
                                               const float* __restrict__ beta,
                                               const int* __restrict__ row_ptr,
                                               const uint* __restrict__ csru,
                                               float* __restrict__ out,
                                               uint* __restrict__ xb_out,
                                               int n) {
    int wid = threadIdx.x >> 6;
    int lane = threadIdx.x & 63;
    int node = blockIdx.x * 4 + wid;
    if (node >= n) return;
    int sub = lane >> 4, c = lane & 15;
    const uint4v* hb4 = (const uint4v*)hb;  // row = 16 chunks of 16B

    float acc[8] = {0.f, 0.f, 0.f, 0.f, 0.f, 0.f, 0.f, 0.f};
    auto ACC8 = [&](uint4v r, float wgt) {
        acc[0] += wgt * __uint_as_float(r.x << 16);
        acc[1] += wgt * __uint_as_float(r.x & 0xffff0000u);
        acc[2] += wgt * __uint_as_float(r.y << 16);
        acc[3] += wgt * __uint_as_float(r.y & 0xffff0000u);
        acc[4] += wgt * __uint_as_float(r.z << 16);
        acc[5] += wgt * __uint_as_float(r.z & 0xffff0000u);
        acc[6] += wgt * __uint_as_float(r.w << 16);
        acc[7] += wgt * __uint_as_float(r.w & 0xffff0000u);
    };

    int beg = row_ptr[node], end = row_ptr[node + 1];
    int j = beg;
    for (; j + 16 <= end; j += 16) {  // 16 edges/iter: 4 gathers in flight
        uint e0 = csru[j + sub];
        uint e1 = csru[j + 4 + sub];
        uint e2 = csru[j + 8 + sub];
        uint e3 = csru[j + 12 + sub];
        uint4v r0 = hb4[(e0 & 0xffffu) * 16 + c];
        uint4v r1 = hb4[(e1 & 0xffffu) * 16 + c];
        uint4v r2 = hb4[(e2 & 0xffffu) * 16 + c];
        uint4v r3 = hb4[(e3 & 0xffffu) * 16 + c];
        ACC8(r0, __uint_as_float(e0 & 0xffff0000u));
        ACC8(r1, __uint_as_float(e1 & 0xffff0000u));
        ACC8(r2, __uint_as_float(e2 & 0xffff0000u));
        ACC8(r3, __uint_as_float(e3 & 0xffff0000u));
    }
    for (; j < end; j += 4) {  // tail, masked (skipped entirely if beg==end)
        int jj = j + sub;
        uint ee = csru[jj < end ? jj : (end - 1)];
        float wgt = (jj < end) ? __uint_as_float(ee & 0xffff0000u) : 0.0f;
        uint idx = (jj < end) ? (ee & 0xffffu) : (uint)node;
        uint4v r = hb4[idx * 16 + c];
        ACC8(r, wgt);
    }
    // reduce the 4 sub-group partials
#pragma unroll
    for (int i = 0; i < 8; ++i) {
        acc[i] += __shfl_xor(acc[i], 16, 64);
        acc[i] += __shfl_xor(acc[i], 32, 64);
    }
    // self term
    {
        uint4v s = hb4[(uint)node * 16 + c];
        ACC8(s, 1.0f);
    }
    // LayerNorm over 128 (16 c-lanes x 8)
    float sum = acc[0] + acc[1] + acc[2] + acc[3] + acc[4] + acc[5] + acc[6] + acc[7];
#pragma unroll
    for (int m = 1; m < 16; m <<= 1) sum += __shfl_xor(sum, m, 64);
    float mean = sum * (1.0f / 128.0f);
    float d0 = acc[0] - mean, d1 = acc[1] - mean, d2 = acc[2] - mean, d3 = acc[3] - mean;
    float d4 = acc[4] - mean, d5 = acc[5] - mean, d6 = acc[6] - mean, d7 = acc[7] - mean;
    float ss = d0 * d0 + d1 * d1 + d2 * d2 + d3 * d3 + d4 * d4 + d5 * d5 + d6 * d6 + d7 * d7;
#pragma unroll
    for (int m = 1; m < 16; m <<= 1) ss += __shfl_xor(ss, m, 64);
    float rstd = rsqrtf(ss * (1.0f / 128.0f) + 1e-5f);
    f32x4 gA = ((const f32x4*)gamma)[c * 2], gB = ((const f32x4*)gamma)[c * 2 + 1];
    f32x4 bA = ((const f32x4*)beta)[c * 2], bB = ((const f32x4*)beta)[c * 2 + 1];
    f32x4 oA, oB;
    oA.x = d0 * rstd * gA.x + bA.x;
    oA.y = d1 * rstd * gA.y + bA.y;
    oA.z = d2 * rstd * gA.z + bA.z;
    oA.w = d3 * rstd * gA.w + bA.w;
    oB.x = d4 * rstd * gB.x + bB.x;
    oB.y = d5 * rstd * gB.y + bB.y;
    oB.z = d6 * rstd * gB.z + bB.z;
    oB.w = d7 * rstd * gB.w + bB.w;
    if (sub == 0) {
        if (out) {
            f32x4* po = (f32x4*)(out + (size_t)node * 128 + c * 8);
            po[0] = oA;
            po[1] = oB;
        }
        if (xb_out) {
            uint4v u;
            u.x = (uint)__bfloat16_as_ushort(__float2bfloat16(oA.x)) |
                  ((uint)__bfloat16_as_ushort(__float2bfloat16(oA.y)) << 16);
            u.y = (uint)__bfloat16_as_ushort(__float2bfloat16(oA.z)) |
                  ((uint)__bfloat16_as_ushort(__float2bfloat16(oA.w)) << 16);
            u.z = (uint)__bfloat16_as_ushort(__float2bfloat16(oB.x)) |
                  ((uint)__bfloat16_as_ushort(__float2bfloat16(oB.y)) << 16);
            u.w = (uint)__bfloat16_as_ushort(__float2bfloat16(oB.z)) |
                  ((uint)__bfloat16_as_ushort(__float2bfloat16(oB.w)) << 16);
            ((uint4v*)xb_out)[node * 16 + c] = u;
        }
    }
}

extern "C" void kernel_launch(void* const* d_in, const int* in_sizes, int n_in,
                              void* d_out, int out_size, void* d_ws, size_t ws_size,
                              hipStream_t stream) {
    const float* x   = (const float*)d_in[0];
    const int*  eidx = (const int*)d_in[1];   // [2,E]: src=eidx, dst=eidx+e
    const float* ew  = (const float*)d_in[2];
    const float* W1  = (const float*)d_in[3];
    const float* b1  = (const float*)d_in[4];
    const float* g1  = (const float*)d_in[5];
    const float* be1 = (const float*)d_in[6];
    const float* W2  = (const float*)d_in[7];
    const float* b2  = (const float*)d_in[8];
    const float* g2  = (const float*)d_in[9];
    const float* be2 = (const float*)d_in[10];
    int n = in_sizes[0] / D;
    int e = in_sizes[2];
    const int* srcp = eidx;
    const int* dstp = eidx + e;

    char* ws = (char*)d_ws;
    size_t off = 0;
    auto alloc = [&](size_t bytes) {
        void* p = ws + off;
        off += (bytes + 255) & ~(size_t)255;
        return p;
    };
    ushort* hb      = (ushort*)alloc((size_t)n * D * sizeof(ushort));
    uint*   xb      = (uint*)alloc((size_t)n * (D / 2) * sizeof(uint));
    int*    row_ptr = (int*)alloc((size_t)(n + 1) * sizeof(int));
    int*    bhist   = (int*)alloc(1024 * sizeof(int));
    int*    boff    = (int*)alloc(1024 * sizeof(int));
    int*    bcursor = (int*)alloc(1024 * sizeof(int));
    short*  WT1     = (short*)alloc(128 * 128 * sizeof(short));
    short*  WT2     = (short*)alloc(128 * 128 * sizeof(short));
    uint2v* csr_tmp = (uint2v*)alloc((size_t)e * sizeof(uint2v));
    uint*   csr4    = (uint*)alloc((size_t)e * sizeof(uint));

    int nb = (n + 63) >> 6;              // 782 buckets (<=1024)
    int nblk = (e + SA - 1) / SA;        // 98 edge blocks

    // ---- build dst-grouped CSR via 2-level counting sort ----
    k_prep<<<129, 256, 0, stream>>>(W1, W2, WT1, WT2, bhist, nb);
    k_bhist<<<nblk, 1024, 0, stream>>>(dstp, e, n, nb, bhist);
    k_bscan<<<1, 1024, 0, stream>>>(bhist, nb, boff, bcursor);
    k_bfill<<<nblk, 1024, 0, stream>>>(srcp, dstp, ew, e, n, nb, bcursor, csr_tmp);
    k_bfinal<<<nb, 256, 0, stream>>>(csr_tmp, boff, n, e, nb, row_ptr, csr4);

    // ---- layer 1 (aggln: no fp32 out write; only bf16 xb for layer-2 GEMM) ----
    k_gemm_mfma<1><<<512, 256, 0, stream>>>(x, nullptr, WT1, b1, hb, n);
    k_aggln<<<(n + 3) / 4, 256, 0, stream>>>(hb, g1, be1, row_ptr, csr4,
                                             nullptr, xb, n);
    // ---- layer 2 ----
    k_gemm_mfma<0><<<512, 256, 0, stream>>>(nullptr, (const short*)xb, WT2, b2, hb, n);
    k_aggln<<<(n + 3) / 4, 256, 0, stream>>>(hb, g2, be2, row_ptr, csr4,
                                             (float*)d_out, nullptr, n);
}

// Round 12
// 133.862 us; speedup vs baseline: 1.2544x; 1.0462x over previous
//
#include <hip/hip_runtime.h>
#include <hip/hip_bf16.h>

// DynamicGCN: 2 layers of { h = relu(x@W+b); h += segment_sum(ew*h[src], dst); LN(h) }
// N=50000, E=800000, D=128.
// r12 (from r11 @ 140us):
//  (1) k_prep removed: gemm self-converts W fp32->bf16 fragments (W is 64KB,
//      L2-resident; one-time per block); gemm1 block 0 zeroes bhist (gemm1 is
//      launch #1, bhist runs after -> safe). 9 -> 8 launches.
//  (2) aggln __launch_bounds__(256,8) (VGPR cap 64, ~45 live -> no spill
//      expected) + self-row gather issued before the edge loop.

#define D 128
#define SA 8192   // edges per block in hist/fill passes

typedef __attribute__((ext_vector_type(8))) short short8;
typedef __attribute__((ext_vector_type(4))) float f32x4;
typedef __attribute__((ext_vector_type(2))) unsigned int uint2v;
typedef __attribute__((ext_vector_type(4))) unsigned int uint4v;

// ---- A: global bucket histogram (bucket = dst>>6) ----
__global__ __launch_bounds__(1024) void k_bhist(const int* __restrict__ dst, int e,
                                                int n, int nb,
                                                int* __restrict__ bhist) {
    __shared__ int lh[784];
    int tid = threadIdx.x;
    for (int i = tid; i < nb; i += 1024) lh[i] = 0;
    __syncthreads();
    int i0 = blockIdx.x * SA;
#pragma unroll
    for (int k = 0; k < SA / 1024; ++k) {
        int i = i0 + k * 1024 + tid;
        if (i < e) {
            int d = dst[i];
            d = min(max(d, 0), n - 1);
            atomicAdd(&lh[d >> 6], 1);
        }
    }
    __syncthreads();
    for (int i = tid; i < nb; i += 1024)
        if (lh[i]) atomicAdd(&bhist[i], lh[i]);
}

// ---- B: exclusive scan of bhist (nb <= 1024); bcursor starts at boff ----
__global__ __launch_bounds__(1024) void k_bscan(const int* __restrict__ bhist, int nb,
                                                int* __restrict__ boff,
                                                int* __restrict__ bcursor) {
    __shared__ int s[1024];
    int t = threadIdx.x;
    int v = (t < nb) ? bhist[t] : 0;
    s[t] = v;
    __syncthreads();
    for (int off = 1; off < 1024; off <<= 1) {
        int u = (t >= off) ? s[t - off] : 0;
        __syncthreads();
        s[t] += u;
        __syncthreads();
    }
    if (t < nb) {
        int ex = s[t] - v;
        boff[t] = ex;
        bcursor[t] = ex;
    }
}

// ---- C: binning fill; (block,bucket) runs reserved once -> XCD-local stores ----
__global__ __launch_bounds__(1024) void k_bfill(const int* __restrict__ src,
                                                const int* __restrict__ dst,
                                                const float* __restrict__ ew, int e,
                                                int n, int nb,
                                                int* __restrict__ bcursor,
                                                uint2v* __restrict__ csr_tmp) {
    __shared__ int lh[784];
    __shared__ int gbase[784];
    int tid = threadIdx.x;
    for (int i = tid; i < nb; i += 1024) lh[i] = 0;
    __syncthreads();
    int i0 = blockIdx.x * SA;
    int bkt[SA / 1024], pos[SA / 1024];
    unsigned pk[SA / 1024];
    float wv[SA / 1024];
#pragma unroll
    for (int k = 0; k < SA / 1024; ++k) {
        int i = i0 + k * 1024 + tid;
        bkt[k] = -1;
        if (i < e) {
            int d = dst[i];
            d = min(max(d, 0), n - 1);
            int s = src[i];
            s = min(max(s, 0), n - 1);
            int b = d >> 6;
            bkt[k] = b;
            pos[k] = atomicAdd(&lh[b], 1);
            pk[k] = (unsigned)s | ((unsigned)(d & 63) << 16);
            wv[k] = ew[i];
        }
    }
    __syncthreads();
    for (int i = tid; i < nb; i += 1024)
        gbase[i] = lh[i] ? atomicAdd(&bcursor[i], lh[i]) : 0;
    __syncthreads();
#pragma unroll
    for (int k = 0; k < SA / 1024; ++k) {
        if (bkt[k] >= 0) {
            int idx = gbase[bkt[k]] + pos[k];
            uint2v en;
            en.x = pk[k];
            en.y = __float_as_uint(wv[k]);
            csr_tmp[idx] = en;
        }
    }
}

// ---- D: per-bucket exact regroup by dst; LDS-staged; emits row_ptr +
// 4B-packed csr {src16 | bf16(w)<<16} ----
#define STG 3072
__global__ __launch_bounds__(256) void k_bfinal(const uint2v* __restrict__ csr_tmp,
                                                const int* __restrict__ boff, int n,
                                                int e, int nb,
                                                int* __restrict__ row_ptr,
                                                uint* __restrict__ csr4) {
    __shared__ uint2v stage[STG];
    __shared__ int dh[64], dcur[64], dscan[64];
    int b = blockIdx.x;
    int tid = threadIdx.x;
    int base = boff[b];
    int endo = (b + 1 < nb) ? boff[b + 1] : e;
    int cnt = endo - base;
    int ndst = min(64, n - b * 64);
    bool st = (cnt <= STG);
    if (tid < 64) { dh[tid] = 0; dcur[tid] = 0; }
    __syncthreads();
    for (int i = tid; i < cnt; i += 256) {
        uint2v en = csr_tmp[base + i];
        if (st) stage[i] = en;
        atomicAdd(&dh[(en.x >> 16) & 63], 1);
    }
    __syncthreads();
    if (tid < 64) {
        int v = dh[tid];
        int incl = v;
#pragma unroll
        for (int off = 1; off < 64; off <<= 1) {
            int u = __shfl_up(incl, off, 64);
            if (tid >= off) incl += u;
        }
        dscan[tid] = incl - v;  // exclusive
        if (tid < ndst) row_ptr[b * 64 + tid] = base + incl - v;
        if (b == nb - 1 && tid == 0) row_ptr[n] = e;
    }
    __syncthreads();
    for (int i = tid; i < cnt; i += 256) {
        uint2v en = st ? stage[i] : csr_tmp[base + i];
        int dlo = (en.x >> 16) & 63;
        int p = atomicAdd(&dcur[dlo], 1);
        uint packed = (en.x & 0xffffu) |
                      ((uint)__bfloat16_as_ushort(
                           __float2bfloat16(__uint_as_float(en.y))) << 16);
        csr4[base + dscan[dlo] + p] = packed;
    }
}

// ---- MFMA GEMM: h_bf16 = relu(x@W + b); block = one 16-row tile/step, waves
// split cols (wave w: n-tiles {w,w+4}); A prefetched one grid-stride ahead.
// B-fragments self-converted from fp32 row-major W (64KB, L2-resident).
// A: row=lane&15, k=(lane>>4)*8+i ; B: col=lane&15 ; D: col=lane&15,
// row=(lane>>4)*4+reg  [r5-verified]
__device__ __forceinline__ short8 cvt8v(f32x4 lo, f32x4 hi) {
    short8 r;
    r[0] = (short)__bfloat16_as_ushort(__float2bfloat16(lo.x));
    r[1] = (short)__bfloat16_as_ushort(__float2bfloat16(lo.y));
    r[2] = (short)__bfloat16_as_ushort(__float2bfloat16(lo.z));
    r[3] = (short)__bfloat16_as_ushort(__float2bfloat16(lo.w));
    r[4] = (short)__bfloat16_as_ushort(__float2bfloat16(hi.x));
    r[5] = (short)__bfloat16_as_ushort(__float2bfloat16(hi.y));
    r[6] = (short)__bfloat16_as_ushort(__float2bfloat16(hi.z));
    r[7] = (short)__bfloat16_as_ushort(__float2bfloat16(hi.w));
    return r;
}

template <int F32IN>
__global__ __launch_bounds__(256) void k_gemm_mfma(const float* __restrict__ xf,
                                                   const short* __restrict__ xb,
                                                   const float* __restrict__ Wf,
                                                   const float* __restrict__ bias,
                                                   ushort* __restrict__ hb, int n,
                                                   int* __restrict__ zbuf, int zn) {
    // gemm1 doubles as the bhist zeroer (runs before k_bhist in the stream)
    if (zbuf && blockIdx.x == 0) {
        for (int i = threadIdx.x; i < zn; i += 256) zbuf[i] = 0;
    }
    int lane = threadIdx.x & 63;
    int w = threadIdx.x >> 6;  // 0..3
    int ln = lane & 15, g = lane >> 4;
    int nt0 = w, nt1 = w + 4;
    short8 bfr0[4], bfr1[4];
#pragma unroll
    for (int kk = 0; kk < 4; ++kk) {
        short8 f0, f1;
#pragma unroll
        for (int i = 0; i < 8; ++i) {
            int k = kk * 32 + g * 8 + i;
            f0[i] = (short)__bfloat16_as_ushort(__float2bfloat16(Wf[k * 128 + nt0 * 16 + ln]));
            f1[i] = (short)__bfloat16_as_ushort(__float2bfloat16(Wf[k * 128 + nt1 * 16 + ln]));
        }
        bfr0[kk] = f0;
        bfr1[kk] = f1;
    }
    float bv0 = bias[nt0 * 16 + ln];
    float bv1 = bias[nt1 * 16 + ln];

    int ntile = n >> 4;  // n % 16 == 0 (50000)
    int t = blockIdx.x;
    if (t >= ntile) return;

    f32x4 cf[8];
    short8 cb[4];
    auto LOADA = [&](int tt, f32x4* bf, short8* bb) {
        int row = tt * 16 + ln;
        if (F32IN) {
            const f32x4* p = (const f32x4*)(xf + (size_t)row * 128 + g * 8);
#pragma unroll
            for (int kk = 0; kk < 4; ++kk) {
                bf[kk * 2] = p[kk * 8];
                bf[kk * 2 + 1] = p[kk * 8 + 1];
            }
        } else {
            const short8* p = (const short8*)(xb + (size_t)row * 128 + g * 8);
#pragma unroll
            for (int kk = 0; kk < 4; ++kk) bb[kk] = p[kk * 4];
        }
    };
    LOADA(t, cf, cb);
    while (true) {
        int tn = t + (int)gridDim.x;
        f32x4 nf[8];
        short8 nb_[4];
        if (tn < ntile) LOADA(tn, nf, nb_);  // prefetch next tile's A
        short8 a[4];
        if (F32IN) {
#pragma unroll
            for (int kk = 0; kk < 4; ++kk) a[kk] = cvt8v(cf[kk * 2], cf[kk * 2 + 1]);
        } else {
#pragma unroll
            for (int kk = 0; kk < 4; ++kk) a[kk] = cb[kk];
        }
        f32x4 acc0 = {}, acc1 = {};
#pragma unroll
        for (int kk = 0; kk < 4; ++kk) {
            acc0 = __builtin_amdgcn_mfma_f32_16x16x32_bf16(a[kk], bfr0[kk], acc0, 0, 0, 0);
            acc1 = __builtin_amdgcn_mfma_f32_16x16x32_bf16(a[kk], bfr1[kk], acc1, 0, 0, 0);
        }
        int r0 = t * 16 + g * 4;
#pragma unroll
        for (int r = 0; r < 4; ++r) {
            float v0 = fmaxf(acc0[r] + bv0, 0.0f);
            float v1 = fmaxf(acc1[r] + bv1, 0.0f);
            hb[(size_t)(r0 + r) * 128 + nt0 * 16 + ln] =
                __bfloat16_as_ushort(__float2bfloat16(v0));
            hb[(size_t)(r0 + r) * 128 + nt1 * 16 + ln] =
                __bfloat16_as_ushort(__float2bfloat16(v1));
        }
        if (tn >= ntile) break;
#pragma unroll
        for (int i = 0; i < 8; ++i) cf[i] = nf[i];
#pragma unroll
        for (int i = 0; i < 4; ++i) cb[i] = nb_[i];
        t = tn;
    }
}

// ---- fused aggregation + LayerNorm; csr entry = {src16 | bf16(w)<<16} ----
// Wave per node; 16 lanes per h-row (sub=lane>>4 handles edge j+4k+sub,
// c=lane&15 owns a 16B chunk). 16-edge loop: 4 independent row-gathers.
// (256,8): VGPR cap 64 for 8 blocks/CU occupancy.
__global__ __launch_bounds__(256, 8) void k_aggln(const ushort* __restrict__ hb,
                                                  const float* __restrict__ gamma,
                                                  const float* __restrict__ beta,
                                                  const int* __restrict__ row_ptr,
                                                  const uint* __restrict__ csru,
                                                  float* __restrict__ out,
                                                  uint* __restrict__ xb_out,
                                                  int n) {
    int wid = threadIdx.x >> 6;
    int lane = threadIdx.x & 63;
    int node = blockIdx.x * 4 + wid;
    if (node >= n) return;
    int sub = lane >> 4, c = lane & 15;
    const uint4v* hb4 = (const uint4v*)hb;  // row = 16 chunks of 16B

    uint4v selfrow = hb4[(uint)node * 16 + c];  // issued early, consumed late

    float acc[8] = {0.f, 0.f, 0.f, 0.f, 0.f, 0.f, 0.f, 0.f};
    auto ACC8 = [&](uint4v r, float wgt) {
        acc[0] += wgt * __uint_as_float(r.x << 16);
        acc[1] += wgt * __uint_as_float(r.x & 0xffff0000u);
        acc[2] += wgt * __uint_as_float(r.y << 16);
        acc[3] += wgt * __uint_as_float(r.y & 0xffff0000u);
        acc[4] += wgt * __uint_as_float(r.z << 16);
        acc[5] += wgt * __uint_as_float(r.z & 0xffff0000u);
        acc[6] += wgt * __uint_as_float(r.w << 16);
        acc[7] += wgt * __uint_as_float(r.w & 0xffff0000u);
    };

    int beg = row_ptr[node], end = row_ptr[node + 1];
    int j = beg;
    for (; j + 16 <= end; j += 16) {  // 16 edges/iter: 4 gathers in flight
        uint e0 = csru[j + sub];
        uint e1 = csru[j + 4 + sub];
        uint e2 = csru[j + 8 + sub];
        uint e3 = csru[j + 12 + sub];
        uint4v r0 = hb4[(e0 & 0xffffu) * 16 + c];
        uint4v r1 = hb4[(e1 & 0xffffu) * 16 + c];
        uint4v r2 = hb4[(e2 & 0xffffu) * 16 + c];
        uint4v r3 = hb4[(e3 & 0xffffu) * 16 + c];
        ACC8(r0, __uint_as_float(e0 & 0xffff0000u));
        ACC8(r1, __uint_as_float(e1 & 0xffff0000u));
        ACC8(r2, __uint_as_float(e2 & 0xffff0000u));
        ACC8(r3, __uint_as_float(e3 & 0xffff0000u));
    }
    for (; j < end; j += 4) {  // tail, masked (skipped entirely if beg==end)
        int jj = j + sub;
        uint ee = csru[jj < end ? jj : (end - 1)];
        float wgt = (jj < end) ? __uint_as_float(ee & 0xffff0000u) : 0.0f;
        uint idx = (jj < end) ? (ee & 0xffffu) : (uint)node;
        uint4v r = hb4[idx * 16 + c];
        ACC8(r, wgt);
    }
    // reduce the 4 sub-group partials
#pragma unroll
    for (int i = 0; i < 8; ++i) {
        acc[i] += __shfl_xor(acc[i], 16, 64);
        acc[i] += __shfl_xor(acc[i], 32, 64);
    }
    // self term (identical across subs post-reduce; added once per lane)
    ACC8(selfrow, 1.0f);
    // LayerNorm over 128 (16 c-lanes x 8)
    float sum = acc[0] + acc[1] + acc[2] + acc[3] + acc[4] + acc[5] + acc[6] + acc[7];
#pragma unroll
    for (int m = 1; m < 16; m <<= 1) sum += __shfl_xor(sum, m, 64);
    float mean = sum * (1.0f / 128.0f);
    float d0 = acc[0] - mean, d1 = acc[1] - mean, d2 = acc[2] - mean, d3 = acc[3] - mean;
    float d4 = acc[4] - mean, d5 = acc[5] - mean, d6 = acc[6] - mean, d7 = acc[7] - mean;
    float ss = d0 * d0 + d1 * d1 + d2 * d2 + d3 * d3 + d4 * d4 + d5 * d5 + d6 * d6 + d7 * d7;
#pragma unroll
    for (int m = 1; m < 16; m <<= 1) ss += __shfl_xor(ss, m, 64);
    float rstd = rsqrtf(ss * (1.0f / 128.0f) + 1e-5f);
    f32x4 gA = ((const f32x4*)gamma)[c * 2], gB = ((const f32x4*)gamma)[c * 2 + 1];
    f32x4 bA = ((const f32x4*)beta)[c * 2], bB = ((const f32x4*)beta)[c * 2 + 1];
    f32x4 oA, oB;
    oA.x = d0 * rstd * gA.x + bA.x;
    oA.y = d1 * rstd * gA.y + bA.y;
    oA.z = d2 * rstd * gA.z + bA.z;
    oA.w = d3 * rstd * gA.w + bA.w;
    oB.x = d4 * rstd * gB.x + bB.x;
    oB.y = d5 * rstd * gB.y + bB.y;
    oB.z = d6 * rstd * gB.z + bB.z;
    oB.w = d7 * rstd * gB.w + bB.w;
    if (sub == 0) {
        if (out) {
            f32x4* po = (f32x4*)(out + (size_t)node * 128 + c * 8);
            po[0] = oA;
            po[1] = oB;
        }
        if (xb_out) {
            uint4v u;
            u.x = (uint)__bfloat16_as_ushort(__float2bfloat16(oA.x)) |
                  ((uint)__bfloat16_as_ushort(__float2bfloat16(oA.y)) << 16);
            u.y = (uint)__bfloat16_as_ushort(__float2bfloat16(oA.z)) |
                  ((uint)__bfloat16_as_ushort(__float2bfloat16(oA.w)) << 16);
            u.z = (uint)__bfloat16_as_ushort(__float2bfloat16(oB.x)) |
                  ((uint)__bfloat16_as_ushort(__float2bfloat16(oB.y)) << 16);
            u.w = (uint)__bfloat16_as_ushort(__float2bfloat16(oB.z)) |
                  ((uint)__bfloat16_as_ushort(__float2bfloat16(oB.w)) << 16);
            ((uint4v*)xb_out)[node * 16 + c] = u;
        }
    }
}

extern "C" void kernel_launch(void* const* d_in, const int* in_sizes, int n_in,
                              void* d_out, int out_size, void* d_ws, size_t ws_size,
                              hipStream_t stream) {
    const float* x   = (const float*)d_in[0];
    const int*  eidx = (const int*)d_in[1];   // [2,E]: src=eidx, dst=eidx+e
    const float* ew  = (const float*)d_in[2];
    const float* W1  = (const float*)d_in[3];
    const float* b1  = (const float*)d_in[4];
    const float* g1  = (const float*)d_in[5];
    const float* be1 = (const float*)d_in[6];
    const float* W2  = (const float*)d_in[7];
    const float* b2  = (const float*)d_in[8];
    const float* g2  = (const float*)d_in[9];
    const float* be2 = (const float*)d_in[10];
    int n = in_sizes[0] / D;
    int e = in_sizes[2];
    const int* srcp = eidx;
    const int* dstp = eidx + e;

    char* ws = (char*)d_ws;
    size_t off = 0;
    auto alloc = [&](size_t bytes) {
        void* p = ws + off;
        off += (bytes + 255) & ~(size_t)255;
        return p;
    };
    ushort* hb      = (ushort*)alloc((size_t)n * D * sizeof(ushort));
    uint*   xb      = (uint*)alloc((size_t)n * (D / 2) * sizeof(uint));
    int*    row_ptr = (int*)alloc((size_t)(n + 1) * sizeof(int));
    int*    bhist   = (int*)alloc(1024 * sizeof(int));
    int*    boff    = (int*)alloc(1024 * sizeof(int));
    int*    bcursor = (int*)alloc(1024 * sizeof(int));
    uint2v* csr_tmp = (uint2v*)alloc((size_t)e * sizeof(uint2v));
    uint*   csr4    = (uint*)alloc((size_t)e * sizeof(uint));

    int nb = (n + 63) >> 6;              // 782 buckets (<=1024)
    int nblk = (e + SA - 1) / SA;        // 98 edge blocks

    // ---- layer-1 GEMM first (also zeroes bhist for the CSR chain below) ----
    k_gemm_mfma<1><<<512, 256, 0, stream>>>(x, nullptr, W1, b1, hb, n, bhist, nb);

    // ---- build dst-grouped CSR via 2-level counting sort ----
    k_bhist<<<nblk, 1024, 0, stream>>>(dstp, e, n, nb, bhist);
    k_bscan<<<1, 1024, 0, stream>>>(bhist, nb, boff, bcursor);
    k_bfill<<<nblk, 1024, 0, stream>>>(srcp, dstp, ew, e, n, nb, bcursor, csr_tmp);
    k_bfinal<<<nb, 256, 0, stream>>>(csr_tmp, boff, n, e, nb, row_ptr, csr4);

    // ---- layer 1 aggregation (writes bf16 xb only) ----
    k_aggln<<<(n + 3) / 4, 256, 0, stream>>>(hb, g1, be1, row_ptr, csr4,
                                             nullptr, xb, n);
    // ---- layer 2 ----
    k_gemm_mfma<0><<<512, 256, 0, stream>>>(nullptr, (const short*)xb, W2, b2, hb, n,
                                            nullptr, 0);
    k_aggln<<<(n + 3) / 4, 256, 0, stream>>>(hb, g2, be2, row_ptr, csr4,
                                             (float*)d_out, nullptr, n);
}